// Round 1
// baseline (4266.089 us; speedup 1.0000x reference)
//
#include <hip/hip_runtime.h>
#include <hip/hip_bf16.h>

// ---------------------------------------------------------------------------
// GCN: h = relu(GCNConv(x,W1,b1)); x1 = relu(GCNConv(h,W2,b2));
//      x2 = meanpool(x1,batch); out = log_softmax(relu(x2@fc1+b)@fc2+b)
// ---------------------------------------------------------------------------

// deg[c] += ew[e]  (self loop +1 added later in dinv kernel)
__global__ void deg_kernel(const int* __restrict__ cols, const float* __restrict__ ew,
                           float* __restrict__ deg, int E) {
    int e = blockIdx.x * 256 + threadIdx.x;
    if (e < E) atomicAdd(&deg[cols[e]], ew[e]);
}

// dinv[i] = rsqrt(deg[i] + 1)   (deg+1 >= 1 > 0 always)
__global__ void dinv_kernel(float* __restrict__ deg, int N) {
    int i = blockIdx.x * 256 + threadIdx.x;
    if (i < N) deg[i] = rsqrtf(deg[i] + 1.0f);
}

// out[M][BN] = A[M][128] @ W[128][BN].  256 threads, 4x4 register tile.
template <int BN>
__global__ void gemm_kernel(const float* __restrict__ A, const float* __restrict__ W,
                            float* __restrict__ out, int M) {
    constexpr int K = 128;
    constexpr int BK = 32;
    constexpr int CG = BN / 4;     // col groups of 4
    constexpr int RG = 256 / CG;   // row groups of 4
    constexpr int BM = RG * 4;     // rows per block (32 for BN=128, 64 for BN=64)
    __shared__ float xs[BM][BK + 4];   // +4 pad: break same-bank between row groups
    __shared__ float ws[BK][BN];
    const int t = threadIdx.x;
    const int cg = t % CG, rg = t / CG;
    const int c0 = cg * 4, r0 = rg * 4;
    const int rowBase = blockIdx.x * BM;
    float acc[4][4] = {};
    for (int k0 = 0; k0 < K; k0 += BK) {
        constexpr int XL = BM * BK / (256 * 4);
        #pragma unroll
        for (int i = 0; i < XL; ++i) {
            int f = (t + i * 256) * 4;
            int rr = f / BK, kk = f % BK;
            int grow = rowBase + rr;
            float4 v = (grow < M) ? *(const float4*)&A[(size_t)grow * K + k0 + kk]
                                  : make_float4(0.f, 0.f, 0.f, 0.f);
            *(float4*)&xs[rr][kk] = v;
        }
        constexpr int WL = BK * BN / (256 * 4);
        #pragma unroll
        for (int i = 0; i < WL; ++i) {
            int f = (t + i * 256) * 4;
            int kk = f / BN, cc = f % BN;
            *(float4*)&ws[kk][cc] = *(const float4*)&W[(size_t)(k0 + kk) * BN + cc];
        }
        __syncthreads();
        #pragma unroll
        for (int kk = 0; kk < BK; ++kk) {
            float4 wv = *(float4*)&ws[kk][c0];
            float xv[4];
            #pragma unroll
            for (int i = 0; i < 4; ++i) xv[i] = xs[r0 + i][kk];
            #pragma unroll
            for (int i = 0; i < 4; ++i) {
                acc[i][0] += xv[i] * wv.x;
                acc[i][1] += xv[i] * wv.y;
                acc[i][2] += xv[i] * wv.z;
                acc[i][3] += xv[i] * wv.w;
            }
        }
        __syncthreads();
    }
    #pragma unroll
    for (int i = 0; i < 4; ++i) {
        int grow = rowBase + r0 + i;
        if (grow < M)
            *(float4*)&out[(size_t)grow * BN + c0] =
                make_float4(acc[i][0], acc[i][1], acc[i][2], acc[i][3]);
    }
}

// agg[col[e]] += xw[row[e]] * (dinv[r]*ew*dinv[c]);  F/4 threads per edge, float4
template <int F>
__global__ void scatter_kernel(const float* __restrict__ xw,
                               const int* __restrict__ rows, const int* __restrict__ cols,
                               const float* __restrict__ ew, const float* __restrict__ dinv,
                               float* __restrict__ agg, int E) {
    constexpr int TPE = F / 4;
    int g = blockIdx.x * 256 + threadIdx.x;
    int e = g / TPE;
    int q = g % TPE;
    if (e >= E) return;
    int r = rows[e], c = cols[e];
    float nrm = dinv[r] * ew[e] * dinv[c];
    float4 v = *(const float4*)&xw[(size_t)r * F + q * 4];
    float* dst = &agg[(size_t)c * F + q * 4];
    atomicAdd(dst + 0, v.x * nrm);
    atomicAdd(dst + 1, v.y * nrm);
    atomicAdd(dst + 2, v.z * nrm);
    atomicAdd(dst + 3, v.w * nrm);
}

// agg = relu(agg + xw*dinv^2 + b)  (adds the self-loop message analytically)
template <int F>
__global__ void bias_relu_kernel(float* __restrict__ agg, const float* __restrict__ xw,
                                 const float* __restrict__ dinv, const float* __restrict__ b,
                                 int N) {
    constexpr int QG = F / 4;
    int g = blockIdx.x * 256 + threadIdx.x;
    int n = g / QG, q = g % QG;
    if (n >= N) return;
    float d2 = dinv[n] * dinv[n];
    float4 a = ((const float4*)agg)[g];
    float4 xv = ((const float4*)xw)[g];
    float4 bb = ((const float4*)b)[q];
    float4 o;
    o.x = fmaxf(a.x + xv.x * d2 + bb.x, 0.f);
    o.y = fmaxf(a.y + xv.y * d2 + bb.y, 0.f);
    o.z = fmaxf(a.z + xv.z * d2 + bb.z, 0.f);
    o.w = fmaxf(a.w + xv.w * d2 + bb.w, 0.f);
    ((float4*)agg)[g] = o;
}

// Fused: x1 = relu(agg2 + xw2*dinv^2 + b2); sums[batch] += x1; cnt[batch] += 1.
// F=64. 16 float4-groups x 16 node streams per block, 16 nodes per stream.
__global__ void pool_kernel(const float* __restrict__ agg2, const float* __restrict__ xw2,
                            const float* __restrict__ dinv, const float* __restrict__ b2,
                            const int* __restrict__ batch,
                            float* __restrict__ sums, float* __restrict__ cnt, int N) {
    constexpr int QG = 16, S = 16, ITER = 16;
    int t = threadIdx.x;
    int q = t % QG, s = t / QG;
    int n0 = blockIdx.x * (S * ITER) + s * ITER;
    float4 bb = ((const float4*)b2)[q];
    float4 acc = make_float4(0.f, 0.f, 0.f, 0.f);
    float cacc = 0.f;
    int gcur = -1;
    for (int i = 0; i < ITER; ++i) {
        int n = n0 + i;
        if (n >= N) break;
        int gid = batch[n];
        if (gid != gcur) {
            if (gcur >= 0) {
                float* dst = &sums[gcur * 64 + q * 4];
                atomicAdd(dst + 0, acc.x);
                atomicAdd(dst + 1, acc.y);
                atomicAdd(dst + 2, acc.z);
                atomicAdd(dst + 3, acc.w);
                if (q == 0) atomicAdd(&cnt[gcur], cacc);
            }
            gcur = gid;
            acc = make_float4(0.f, 0.f, 0.f, 0.f);
            cacc = 0.f;
        }
        float d2 = dinv[n] * dinv[n];
        float4 a = ((const float4*)agg2)[n * QG + q];
        float4 xv = ((const float4*)xw2)[n * QG + q];
        acc.x += fmaxf(a.x + xv.x * d2 + bb.x, 0.f);
        acc.y += fmaxf(a.y + xv.y * d2 + bb.y, 0.f);
        acc.z += fmaxf(a.z + xv.z * d2 + bb.z, 0.f);
        acc.w += fmaxf(a.w + xv.w * d2 + bb.w, 0.f);
        if (q == 0) cacc += 1.f;
    }
    if (gcur >= 0) {
        float* dst = &sums[gcur * 64 + q * 4];
        atomicAdd(dst + 0, acc.x);
        atomicAdd(dst + 1, acc.y);
        atomicAdd(dst + 2, acc.z);
        atomicAdd(dst + 3, acc.w);
        if (q == 0) atomicAdd(&cnt[gcur], cacc);
    }
}

// Final MLP head + log_softmax, one block. G=64 graphs.
__global__ void head_kernel(const float* __restrict__ sums, const float* __restrict__ cnt,
                            const float* __restrict__ fc1W, const float* __restrict__ fc1b,
                            const float* __restrict__ fc2W, const float* __restrict__ fc2b,
                            float* __restrict__ out) {
    __shared__ float x2[64 * 64];
    __shared__ float h[64 * 128];
    __shared__ float logits[64 * 2];
    int t = threadIdx.x;
    for (int i = t; i < 64 * 64; i += 256) {
        int g = i / 64;
        x2[i] = sums[i] / fmaxf(cnt[g], 1.f);
    }
    __syncthreads();
    for (int i = t; i < 64 * 128; i += 256) {
        int g = i / 128, k = i % 128;
        float a = fc1b[k];
        #pragma unroll 8
        for (int j = 0; j < 64; ++j) a += x2[g * 64 + j] * fc1W[j * 128 + k];
        h[i] = fmaxf(a, 0.f);
    }
    __syncthreads();
    if (t < 128) {
        int g = t / 2, m = t % 2;
        float a = fc2b[m];
        #pragma unroll 8
        for (int k = 0; k < 128; ++k) a += h[g * 128 + k] * fc2W[k * 2 + m];
        logits[t] = a;
    }
    __syncthreads();
    if (t < 128) {
        int g = t / 2, m = t % 2;
        float l0 = logits[g * 2 + 0], l1 = logits[g * 2 + 1];
        float mx = fmaxf(l0, l1);
        float lse = mx + logf(expf(l0 - mx) + expf(l1 - mx));
        out[t] = (m == 0 ? l0 : l1) - lse;
    }
}

extern "C" void kernel_launch(void* const* d_in, const int* in_sizes, int n_in,
                              void* d_out, int out_size, void* d_ws, size_t ws_size,
                              hipStream_t stream) {
    const float* x      = (const float*)d_in[0];
    const int*   eidx   = (const int*)d_in[1];
    const float* ew     = (const float*)d_in[2];
    const int*   batch  = (const int*)d_in[3];
    const float* W1     = (const float*)d_in[4];
    const float* b1     = (const float*)d_in[5];
    const float* W2     = (const float*)d_in[6];
    const float* b2     = (const float*)d_in[7];
    const float* fc1W   = (const float*)d_in[8];
    const float* fc1b   = (const float*)d_in[9];
    const float* fc2W   = (const float*)d_in[10];
    const float* fc2b   = (const float*)d_in[11];
    float* out = (float*)d_out;

    const int N = in_sizes[3];          // 50000 nodes
    const int E = in_sizes[2];          // 1600000 edges
    const int G = 64;                   // graphs
    const int* rows = eidx;
    const int* cols = eidx + E;

    float* ws = (float*)d_ws;
    size_t off = 0;
    float* deg  = ws + off; off += ((size_t)N + 15) & ~(size_t)15;
    float* agg1 = ws + off; off += (size_t)N * 128;   // later becomes h
    float* agg2 = ws + off; off += (size_t)N * 64;
    float* sums = ws + off; off += (size_t)G * 64;
    float* cntp = ws + off; off += 16;
    size_t zfloats = off;                              // everything above starts at 0
    float* xw1 = ws + off; off += (size_t)N * 128;
    float* xw2 = ws + off; off += (size_t)N * 64;
    (void)ws_size;

    hipMemsetAsync(d_ws, 0, zfloats * sizeof(float), stream);

    deg_kernel<<<(E + 255) / 256, 256, 0, stream>>>(cols, ew, deg, E);
    dinv_kernel<<<(N + 255) / 256, 256, 0, stream>>>(deg, N);

    // Layer 1: xw1 = x @ W1 ; scatter ; agg1 = relu(agg1 + xw1*dinv^2 + b1) = h
    gemm_kernel<128><<<(N + 31) / 32, 256, 0, stream>>>(x, W1, xw1, N);
    {
        long long thr = (long long)E * 32;
        scatter_kernel<128><<<(int)((thr + 255) / 256), 256, 0, stream>>>(
            xw1, rows, cols, ew, deg, agg1, E);
    }
    bias_relu_kernel<128><<<(N * 32 + 255) / 256, 256, 0, stream>>>(agg1, xw1, deg, b1, N);

    // Layer 2: xw2 = h @ W2 ; scatter ; fused relu+pool (never materialize x1)
    gemm_kernel<64><<<(N + 63) / 64, 256, 0, stream>>>(agg1, W2, xw2, N);
    {
        long long thr = (long long)E * 16;
        scatter_kernel<64><<<(int)((thr + 255) / 256), 256, 0, stream>>>(
            xw2, rows, cols, ew, deg, agg2, E);
    }
    pool_kernel<<<(N + 255) / 256, 256, 0, stream>>>(agg2, xw2, deg, b2, batch, sums, cntp, N);

    head_kernel<<<1, 256, 0, stream>>>(sums, cntp, fc1W, fc1b, fc2W, fc2b, out);
}

// Round 2
// 721.861 us; speedup vs baseline: 5.9099x; 5.9099x over previous
//
#include <hip/hip_runtime.h>
#include <hip/hip_bf16.h>

// ---------------------------------------------------------------------------
// GCN: h = relu(GCNConv(x,W1,b1)); x1 = relu(GCNConv(h,W2,b2));
//      x2 = meanpool(x1,batch); out = log_softmax(relu(x2@fc1+b)@fc2+b)
//
// R2: replaced 51.2M scattered fp32 atomics (3.2 GB of 64B coherent-point
// transactions, 2650+1300 us) with a per-call CSR build (int atomics only)
// + gather-style aggregation (coalesced 512B row reads, zero float atomics).
// ---------------------------------------------------------------------------

// deg[c] += ew[e]; ecnt[c] += 1   (self loop +1 added later in dinv kernel)
__global__ void degcnt_kernel(const int* __restrict__ cols, const float* __restrict__ ew,
                              float* __restrict__ deg, int* __restrict__ ecnt, int E) {
    int e = blockIdx.x * 256 + threadIdx.x;
    if (e < E) {
        int c = cols[e];
        atomicAdd(&deg[c], ew[e]);
        atomicAdd(&ecnt[c], 1);
    }
}

// dinv[i] = rsqrt(deg[i] + 1)   (deg+1 >= 1 > 0 always)
__global__ void dinv_kernel(float* __restrict__ deg, int N) {
    int i = blockIdx.x * 256 + threadIdx.x;
    if (i < N) deg[i] = rsqrtf(deg[i] + 1.0f);
}

// Exclusive prefix sum of ecnt[N] -> rowptr[N+1], also copies into cursor[N].
// Single block of 1024 threads, each handling a contiguous chunk.
__global__ void scan_kernel(const int* __restrict__ ecnt, int* __restrict__ rowptr,
                            int* __restrict__ cursor, int N) {
    __shared__ int part[1024];
    const int t = threadIdx.x;
    const int chunk = (N + 1023) / 1024;
    const int base = t * chunk;
    int s = 0;
    for (int i = 0; i < chunk; ++i) {
        int idx = base + i;
        if (idx < N) s += ecnt[idx];
    }
    part[t] = s;
    __syncthreads();
    for (int off = 1; off < 1024; off <<= 1) {
        int add = (t >= off) ? part[t - off] : 0;
        __syncthreads();
        part[t] += add;
        __syncthreads();
    }
    int run = part[t] - s;   // exclusive prefix of this thread's chunk
    for (int i = 0; i < chunk; ++i) {
        int idx = base + i;
        if (idx < N) {
            rowptr[idx] = run;
            cursor[idx] = run;
            run += ecnt[idx];
        }
    }
    if (t == 1023) rowptr[N] = part[1023];
}

// Bucket edges by destination: erec[pos] = (row, dinv[r]*ew*dinv[c])
__global__ void place_kernel(const int* __restrict__ rows, const int* __restrict__ cols,
                             const float* __restrict__ ew, const float* __restrict__ dinv,
                             int* __restrict__ cursor, int2* __restrict__ erec, int E) {
    int e = blockIdx.x * 256 + threadIdx.x;
    if (e >= E) return;
    int r = rows[e], c = cols[e];
    int pos = atomicAdd(&cursor[c], 1);
    float coef = dinv[r] * ew[e] * dinv[c];
    erec[pos] = make_int2(r, __float_as_int(coef));
}

// out[M][BN] = A[M][128] @ W[128][BN].  256 threads, 4x4 register tile.
template <int BN>
__global__ void gemm_kernel(const float* __restrict__ A, const float* __restrict__ W,
                            float* __restrict__ out, int M) {
    constexpr int K = 128;
    constexpr int BK = 32;
    constexpr int CG = BN / 4;     // col groups of 4
    constexpr int RG = 256 / CG;   // row groups of 4
    constexpr int BM = RG * 4;     // rows per block
    __shared__ float xs[BM][BK + 4];
    __shared__ float ws[BK][BN];
    const int t = threadIdx.x;
    const int cg = t % CG, rg = t / CG;
    const int c0 = cg * 4, r0 = rg * 4;
    const int rowBase = blockIdx.x * BM;
    float acc[4][4] = {};
    for (int k0 = 0; k0 < K; k0 += BK) {
        constexpr int XL = BM * BK / (256 * 4);
        #pragma unroll
        for (int i = 0; i < XL; ++i) {
            int f = (t + i * 256) * 4;
            int rr = f / BK, kk = f % BK;
            int grow = rowBase + rr;
            float4 v = (grow < M) ? *(const float4*)&A[(size_t)grow * K + k0 + kk]
                                  : make_float4(0.f, 0.f, 0.f, 0.f);
            *(float4*)&xs[rr][kk] = v;
        }
        constexpr int WL = BK * BN / (256 * 4);
        #pragma unroll
        for (int i = 0; i < WL; ++i) {
            int f = (t + i * 256) * 4;
            int kk = f / BN, cc = f % BN;
            *(float4*)&ws[kk][cc] = *(const float4*)&W[(size_t)(k0 + kk) * BN + cc];
        }
        __syncthreads();
        #pragma unroll
        for (int kk = 0; kk < BK; ++kk) {
            float4 wv = *(float4*)&ws[kk][c0];
            float xv[4];
            #pragma unroll
            for (int i = 0; i < 4; ++i) xv[i] = xs[r0 + i][kk];
            #pragma unroll
            for (int i = 0; i < 4; ++i) {
                acc[i][0] += xv[i] * wv.x;
                acc[i][1] += xv[i] * wv.y;
                acc[i][2] += xv[i] * wv.z;
                acc[i][3] += xv[i] * wv.w;
            }
        }
        __syncthreads();
    }
    #pragma unroll
    for (int i = 0; i < 4; ++i) {
        int grow = rowBase + r0 + i;
        if (grow < M)
            *(float4*)&out[(size_t)grow * BN + c0] =
                make_float4(acc[i][0], acc[i][1], acc[i][2], acc[i][3]);
    }
}

// F=128 aggregation: one wave per node, lane owns float2. Coalesced 512B row
// gathers, zero float atomics. Epilogue: + xw[i]*dinv^2 + b, relu.
__global__ void gather128_kernel(const float* __restrict__ xw, const int2* __restrict__ erec,
                                 const int* __restrict__ rowptr, const float* __restrict__ dinv,
                                 const float* __restrict__ b, float* __restrict__ out, int N) {
    const int w = threadIdx.x >> 6;
    const int lane = threadIdx.x & 63;
    const int i = blockIdx.x * 4 + w;
    if (i >= N) return;
    const int s = rowptr[i], e = rowptr[i + 1];
    const float2* src = (const float2*)xw;
    float2 acc = make_float2(0.f, 0.f);
    int j = s;
    for (; j + 4 <= e; j += 4) {
        int2 r0 = erec[j], r1 = erec[j + 1], r2 = erec[j + 2], r3 = erec[j + 3];
        float2 v0 = src[(size_t)r0.x * 64 + lane];
        float2 v1 = src[(size_t)r1.x * 64 + lane];
        float2 v2 = src[(size_t)r2.x * 64 + lane];
        float2 v3 = src[(size_t)r3.x * 64 + lane];
        float c0 = __int_as_float(r0.y), c1 = __int_as_float(r1.y);
        float c2 = __int_as_float(r2.y), c3 = __int_as_float(r3.y);
        acc.x += v0.x * c0 + v1.x * c1 + v2.x * c2 + v3.x * c3;
        acc.y += v0.y * c0 + v1.y * c1 + v2.y * c2 + v3.y * c3;
    }
    for (; j < e; ++j) {
        int2 r = erec[j];
        float2 v = src[(size_t)r.x * 64 + lane];
        float c = __int_as_float(r.y);
        acc.x += v.x * c;
        acc.y += v.y * c;
    }
    float d = dinv[i], d2 = d * d;
    float2 xv = src[(size_t)i * 64 + lane];
    float2 bb = ((const float2*)b)[lane];
    float2 o;
    o.x = fmaxf(acc.x + xv.x * d2 + bb.x, 0.f);
    o.y = fmaxf(acc.y + xv.y * d2 + bb.y, 0.f);
    ((float2*)out)[(size_t)i * 64 + lane] = o;
}

// F=64 aggregation: one wave per node, lane owns 1 float.
__global__ void gather64_kernel(const float* __restrict__ xw, const int2* __restrict__ erec,
                                const int* __restrict__ rowptr, const float* __restrict__ dinv,
                                const float* __restrict__ b, float* __restrict__ out, int N) {
    const int w = threadIdx.x >> 6;
    const int lane = threadIdx.x & 63;
    const int i = blockIdx.x * 4 + w;
    if (i >= N) return;
    const int s = rowptr[i], e = rowptr[i + 1];
    float acc = 0.f;
    int j = s;
    for (; j + 4 <= e; j += 4) {
        int2 r0 = erec[j], r1 = erec[j + 1], r2 = erec[j + 2], r3 = erec[j + 3];
        float v0 = xw[(size_t)r0.x * 64 + lane];
        float v1 = xw[(size_t)r1.x * 64 + lane];
        float v2 = xw[(size_t)r2.x * 64 + lane];
        float v3 = xw[(size_t)r3.x * 64 + lane];
        acc += v0 * __int_as_float(r0.y) + v1 * __int_as_float(r1.y)
             + v2 * __int_as_float(r2.y) + v3 * __int_as_float(r3.y);
    }
    for (; j < e; ++j) {
        int2 r = erec[j];
        acc += xw[(size_t)r.x * 64 + lane] * __int_as_float(r.y);
    }
    float d = dinv[i];
    float o = fmaxf(acc + xw[(size_t)i * 64 + lane] * d * d + b[lane], 0.f);
    out[(size_t)i * 64 + lane] = o;
}

// sums[batch[n]] += x1[n]; cnt[batch[n]] += 1.  Exploits sorted batch:
// per-thread segment accumulation over 16 nodes, atomics only at boundaries.
__global__ void pool_kernel(const float* __restrict__ x1, const int* __restrict__ batch,
                            float* __restrict__ sums, float* __restrict__ cnt, int N) {
    constexpr int QG = 16, S = 16, ITER = 16;
    int t = threadIdx.x;
    int q = t % QG, s = t / QG;
    int n0 = blockIdx.x * (S * ITER) + s * ITER;
    float4 acc = make_float4(0.f, 0.f, 0.f, 0.f);
    float cacc = 0.f;
    int gcur = -1;
    for (int i = 0; i < ITER; ++i) {
        int n = n0 + i;
        if (n >= N) break;
        int gid = batch[n];
        if (gid != gcur) {
            if (gcur >= 0) {
                float* dst = &sums[gcur * 64 + q * 4];
                atomicAdd(dst + 0, acc.x);
                atomicAdd(dst + 1, acc.y);
                atomicAdd(dst + 2, acc.z);
                atomicAdd(dst + 3, acc.w);
                if (q == 0) atomicAdd(&cnt[gcur], cacc);
            }
            gcur = gid;
            acc = make_float4(0.f, 0.f, 0.f, 0.f);
            cacc = 0.f;
        }
        float4 a = ((const float4*)x1)[n * QG + q];
        acc.x += a.x; acc.y += a.y; acc.z += a.z; acc.w += a.w;
        if (q == 0) cacc += 1.f;
    }
    if (gcur >= 0) {
        float* dst = &sums[gcur * 64 + q * 4];
        atomicAdd(dst + 0, acc.x);
        atomicAdd(dst + 1, acc.y);
        atomicAdd(dst + 2, acc.z);
        atomicAdd(dst + 3, acc.w);
        if (q == 0) atomicAdd(&cnt[gcur], cacc);
    }
}

// Final MLP head + log_softmax, one block. G=64 graphs.
__global__ void head_kernel(const float* __restrict__ sums, const float* __restrict__ cnt,
                            const float* __restrict__ fc1W, const float* __restrict__ fc1b,
                            const float* __restrict__ fc2W, const float* __restrict__ fc2b,
                            float* __restrict__ out) {
    __shared__ float x2[64 * 64];
    __shared__ float h[64 * 128];
    __shared__ float logits[64 * 2];
    int t = threadIdx.x;
    for (int i = t; i < 64 * 64; i += 256) {
        int g = i / 64;
        x2[i] = sums[i] / fmaxf(cnt[g], 1.f);
    }
    __syncthreads();
    for (int i = t; i < 64 * 128; i += 256) {
        int g = i / 128, k = i % 128;
        float a = fc1b[k];
        #pragma unroll 8
        for (int j = 0; j < 64; ++j) a += x2[g * 64 + j] * fc1W[j * 128 + k];
        h[i] = fmaxf(a, 0.f);
    }
    __syncthreads();
    if (t < 128) {
        int g = t / 2, m = t % 2;
        float a = fc2b[m];
        #pragma unroll 8
        for (int k = 0; k < 128; ++k) a += h[g * 128 + k] * fc2W[k * 2 + m];
        logits[t] = a;
    }
    __syncthreads();
    if (t < 128) {
        int g = t / 2, m = t % 2;
        float l0 = logits[g * 2 + 0], l1 = logits[g * 2 + 1];
        float mx = fmaxf(l0, l1);
        float lse = mx + logf(expf(l0 - mx) + expf(l1 - mx));
        out[t] = (m == 0 ? l0 : l1) - lse;
    }
}

extern "C" void kernel_launch(void* const* d_in, const int* in_sizes, int n_in,
                              void* d_out, int out_size, void* d_ws, size_t ws_size,
                              hipStream_t stream) {
    const float* x      = (const float*)d_in[0];
    const int*   eidx   = (const int*)d_in[1];
    const float* ew     = (const float*)d_in[2];
    const int*   batch  = (const int*)d_in[3];
    const float* W1     = (const float*)d_in[4];
    const float* b1     = (const float*)d_in[5];
    const float* W2     = (const float*)d_in[6];
    const float* b2     = (const float*)d_in[7];
    const float* fc1W   = (const float*)d_in[8];
    const float* fc1b   = (const float*)d_in[9];
    const float* fc2W   = (const float*)d_in[10];
    const float* fc2b   = (const float*)d_in[11];
    float* out = (float*)d_out;

    const int N = in_sizes[3];          // 50000 nodes
    const int E = in_sizes[2];          // 1600000 edges
    const int* rows = eidx;
    const int* cols = eidx + E;

    float* ws = (float*)d_ws;
    size_t off = 0;
    auto alloc = [&](size_t n) { float* p = ws + off; off += (n + 15) & ~(size_t)15; return p; };
    // --- zero-initialized region (memset below) ---
    float* deg    = alloc(N);
    int*   ecnt   = (int*)alloc(N);
    float* sums   = alloc(64 * 64);
    float* cntf   = alloc(16);
    size_t zfloats = off;
    // --- rest ---
    int*   rowptr = (int*)alloc(N + 1);
    int*   cursor = (int*)alloc(N);
    int2*  erec   = (int2*)alloc((size_t)E * 2);
    float* bufA   = alloc((size_t)N * 128);   // xw1; later xw2 (lo half) + x1 (hi half)
    float* bufB   = alloc((size_t)N * 128);   // h
    float* xw1 = bufA;
    float* h   = bufB;
    float* xw2 = bufA;
    float* x1  = bufA + (size_t)N * 64;
    (void)ws_size;

    hipMemsetAsync(d_ws, 0, zfloats * sizeof(float), stream);

    // CSR build (by destination) + degree normalization
    degcnt_kernel<<<(E + 255) / 256, 256, 0, stream>>>(cols, ew, deg, ecnt, E);
    dinv_kernel<<<(N + 255) / 256, 256, 0, stream>>>(deg, N);
    scan_kernel<<<1, 1024, 0, stream>>>(ecnt, rowptr, cursor, N);
    place_kernel<<<(E + 255) / 256, 256, 0, stream>>>(rows, cols, ew, deg, cursor, erec, E);

    // Layer 1: xw1 = x @ W1 ; h = relu(gather(xw1) + xw1*dinv^2 + b1)
    gemm_kernel<128><<<(N + 31) / 32, 256, 0, stream>>>(x, W1, xw1, N);
    gather128_kernel<<<(N + 3) / 4, 256, 0, stream>>>(xw1, erec, rowptr, deg, b1, h, N);

    // Layer 2: xw2 = h @ W2 ; x1 = relu(gather(xw2) + xw2*dinv^2 + b2)
    gemm_kernel<64><<<(N + 63) / 64, 256, 0, stream>>>(h, W2, xw2, N);
    gather64_kernel<<<(N + 3) / 4, 256, 0, stream>>>(xw2, erec, rowptr, deg, b2, x1, N);

    // Mean-pool + head
    pool_kernel<<<(N + 255) / 256, 256, 0, stream>>>(x1, batch, sums, cntf, N);
    head_kernel<<<1, 256, 0, stream>>>(sums, cntf, fc1W, fc1b, fc2W, fc2b, out);
}

// Round 3
// 536.545 us; speedup vs baseline: 7.9510x; 1.3454x over previous
//
#include <hip/hip_runtime.h>
#include <hip/hip_bf16.h>

// ---------------------------------------------------------------------------
// GCN: h = relu(GCNConv(x,W1,b1)); x1 = relu(GCNConv(h,W2,b2));
//      x2 = meanpool(x1,batch); out = log_softmax(relu(x2@fc1+b)@fc2+b)
//
// R3: CSR build with 1.6M atomics total (was 4.8M): fixed-capacity (64)
// direct bucketing, deg computed per-bucket (no atomics), no prefix scan.
// Overflow (>64 in-edges, ~1% chance for this input) handled correctly via
// flag-gated fixup kernels. Gathers use float4 lanes + multi-edge waves.
// ---------------------------------------------------------------------------

#define CAP 64
#define OVFCAP 8192

// pos = cnt[c]++; slot[c*CAP+pos] = (row, ew_bits); overflow -> list + flag
__global__ void place_kernel(const int* __restrict__ rows, const int* __restrict__ cols,
                             const float* __restrict__ ew, int* __restrict__ cnt,
                             int2* __restrict__ slot, int4* __restrict__ ovf,
                             int* __restrict__ ovfcnt, int* __restrict__ flag, int E) {
    int e = blockIdx.x * 256 + threadIdx.x;
    if (e >= E) return;
    int r = rows[e], c = cols[e];
    int pos = atomicAdd(&cnt[c], 1);
    if (pos < CAP) {
        slot[(size_t)c * CAP + pos] = make_int2(r, __float_as_int(ew[e]));
    } else {
        *flag = 1;
        int o = atomicAdd(ovfcnt, 1);
        if (o < OVFCAP) ovf[o] = make_int4(r, c, __float_as_int(ew[e]), 0);
    }
}

// deg[i] = sum of ew over bucket i (wave per node, butterfly reduce)
__global__ void degfin_kernel(const int2* __restrict__ slot, const int* __restrict__ cnt,
                              float* __restrict__ deg, int N) {
    const int w = threadIdx.x >> 6, lane = threadIdx.x & 63;
    const int i = blockIdx.x * 4 + w;
    if (i >= N) return;
    int m = cnt[i]; if (m > CAP) m = CAP;
    float v = 0.f;
    if (lane < m) v = __int_as_float(slot[(size_t)i * CAP + lane].y);
    #pragma unroll
    for (int off = 1; off < 64; off <<= 1) v += __shfl_xor(v, off);
    if (lane == 0) deg[i] = v;
}

// overflow edges' weights into deg (normally ovfcnt==0 -> instant exit)
__global__ void ovfdeg_kernel(const int4* __restrict__ ovf, const int* __restrict__ ovfcnt,
                              float* __restrict__ deg) {
    int n = *ovfcnt; if (n > OVFCAP) n = OVFCAP;
    for (int k = threadIdx.x; k < n; k += 256)
        atomicAdd(&deg[ovf[k].y], __int_as_float(ovf[k].z));
}

// dinv[i] = rsqrt(deg[i] + 1)   (self-loop weight 1)
__global__ void dinv_kernel(float* __restrict__ deg, int N) {
    int i = blockIdx.x * 256 + threadIdx.x;
    if (i < N) deg[i] = rsqrtf(deg[i] + 1.0f);
}

// slot coef := ew * dinv[row]   (wave handles one node's CAP slots)
__global__ void rescale_kernel(int2* __restrict__ slot, const int* __restrict__ cnt,
                               const float* __restrict__ dinv, int N) {
    int g = blockIdx.x * 256 + threadIdx.x;
    int c = g >> 6, p = g & 63;
    if (c >= N) return;
    int m = cnt[c]; if (m > CAP) m = CAP;
    if (p < m) {
        int2 rec = slot[g];
        slot[g] = make_int2(rec.x, __float_as_int(__int_as_float(rec.y) * dinv[rec.x]));
    }
}

// out[M][BN] = A[M][128] @ W[128][BN].  256 threads, 4x4 register tile.
template <int BN>
__global__ void gemm_kernel(const float* __restrict__ A, const float* __restrict__ W,
                            float* __restrict__ out, int M) {
    constexpr int K = 128;
    constexpr int BK = 32;
    constexpr int CG = BN / 4;
    constexpr int RG = 256 / CG;
    constexpr int BM = RG * 4;
    __shared__ float xs[BM][BK + 4];
    __shared__ float ws[BK][BN];
    const int t = threadIdx.x;
    const int cg = t % CG, rg = t / CG;
    const int c0 = cg * 4, r0 = rg * 4;
    const int rowBase = blockIdx.x * BM;
    float acc[4][4] = {};
    for (int k0 = 0; k0 < K; k0 += BK) {
        constexpr int XL = BM * BK / (256 * 4);
        #pragma unroll
        for (int i = 0; i < XL; ++i) {
            int f = (t + i * 256) * 4;
            int rr = f / BK, kk = f % BK;
            int grow = rowBase + rr;
            float4 v = (grow < M) ? *(const float4*)&A[(size_t)grow * K + k0 + kk]
                                  : make_float4(0.f, 0.f, 0.f, 0.f);
            *(float4*)&xs[rr][kk] = v;
        }
        constexpr int WL = BK * BN / (256 * 4);
        #pragma unroll
        for (int i = 0; i < WL; ++i) {
            int f = (t + i * 256) * 4;
            int kk = f / BN, cc = f % BN;
            *(float4*)&ws[kk][cc] = *(const float4*)&W[(size_t)(k0 + kk) * BN + cc];
        }
        __syncthreads();
        #pragma unroll
        for (int kk = 0; kk < BK; ++kk) {
            float4 wv = *(float4*)&ws[kk][c0];
            float xv[4];
            #pragma unroll
            for (int i = 0; i < 4; ++i) xv[i] = xs[r0 + i][kk];
            #pragma unroll
            for (int i = 0; i < 4; ++i) {
                acc[i][0] += xv[i] * wv.x;
                acc[i][1] += xv[i] * wv.y;
                acc[i][2] += xv[i] * wv.z;
                acc[i][3] += xv[i] * wv.w;
            }
        }
        __syncthreads();
    }
    #pragma unroll
    for (int i = 0; i < 4; ++i) {
        int grow = rowBase + r0 + i;
        if (grow < M)
            *(float4*)&out[(size_t)grow * BN + c0] =
                make_float4(acc[i][0], acc[i][1], acc[i][2], acc[i][3]);
    }
}

// Aggregation: wave per node; lane owns float4; EPW edges processed per wave
// concurrently, combined via shfl_xor. flag==0 (normal): fused epilogue
// relu(dinv*acc + xw*dinv^2 + b). flag==1: raw S-sum written, fixups follow.
template <int F>
__global__ void gather_kernel(const float* __restrict__ xw, const int2* __restrict__ slot,
                              const int* __restrict__ cnt, const float* __restrict__ dinv,
                              const float* __restrict__ b, const int* __restrict__ flag,
                              float* __restrict__ out, int N) {
    constexpr int LG = F / 4;        // lanes per edge-slot
    constexpr int EPW = 64 / LG;     // edges in flight per wave
    const int w = threadIdx.x >> 6, lane = threadIdx.x & 63;
    const int i = blockIdx.x * 4 + w;
    if (i >= N) return;
    const int sub = lane / LG, cg = lane % LG;
    const int fl = *flag;
    int m = cnt[i]; if (m > CAP) m = CAP;
    const int2* bucket = slot + (size_t)i * CAP;
    float4 acc = make_float4(0.f, 0.f, 0.f, 0.f);
    int jj = 0;
    for (; jj + 4 * EPW <= m; jj += 4 * EPW) {
        int2 r0 = bucket[jj + 0 * EPW + sub];
        int2 r1 = bucket[jj + 1 * EPW + sub];
        int2 r2 = bucket[jj + 2 * EPW + sub];
        int2 r3 = bucket[jj + 3 * EPW + sub];
        float4 v0 = *(const float4*)&xw[(size_t)r0.x * F + cg * 4];
        float4 v1 = *(const float4*)&xw[(size_t)r1.x * F + cg * 4];
        float4 v2 = *(const float4*)&xw[(size_t)r2.x * F + cg * 4];
        float4 v3 = *(const float4*)&xw[(size_t)r3.x * F + cg * 4];
        float c0 = __int_as_float(r0.y), c1 = __int_as_float(r1.y);
        float c2 = __int_as_float(r2.y), c3 = __int_as_float(r3.y);
        acc.x += v0.x * c0 + v1.x * c1 + v2.x * c2 + v3.x * c3;
        acc.y += v0.y * c0 + v1.y * c1 + v2.y * c2 + v3.y * c3;
        acc.z += v0.z * c0 + v1.z * c1 + v2.z * c2 + v3.z * c3;
        acc.w += v0.w * c0 + v1.w * c1 + v2.w * c2 + v3.w * c3;
    }
    for (; jj < m; jj += EPW) {
        int j = jj + sub;
        if (j < m) {
            int2 r = bucket[j];
            float4 v = *(const float4*)&xw[(size_t)r.x * F + cg * 4];
            float c = __int_as_float(r.y);
            acc.x += v.x * c; acc.y += v.y * c; acc.z += v.z * c; acc.w += v.w * c;
        }
    }
    #pragma unroll
    for (int off = LG; off < 64; off <<= 1) {
        acc.x += __shfl_xor(acc.x, off);
        acc.y += __shfl_xor(acc.y, off);
        acc.z += __shfl_xor(acc.z, off);
        acc.w += __shfl_xor(acc.w, off);
    }
    if (sub == 0) {
        float4* dst = (float4*)&out[(size_t)i * F + cg * 4];
        if (fl == 0) {
            float d = dinv[i], d2 = d * d;
            float4 xv = *(const float4*)&xw[(size_t)i * F + cg * 4];
            float4 bb = ((const float4*)b)[cg];
            float4 o;
            o.x = fmaxf(acc.x * d + xv.x * d2 + bb.x, 0.f);
            o.y = fmaxf(acc.y * d + xv.y * d2 + bb.y, 0.f);
            o.z = fmaxf(acc.z * d + xv.z * d2 + bb.z, 0.f);
            o.w = fmaxf(acc.w * d + xv.w * d2 + bb.w, 0.f);
            *dst = o;
        } else {
            *dst = acc;   // raw S-sum; ovfmsg + epi kernels finish
        }
    }
}

// flag==1 only: add overflow-edge messages (S-space) via atomics
template <int F>
__global__ void ovfmsg_kernel(const float* __restrict__ xw, const int4* __restrict__ ovf,
                              const int* __restrict__ ovfcnt, const float* __restrict__ dinv,
                              const int* __restrict__ flag, float* __restrict__ out) {
    if (*flag == 0) return;
    int n = *ovfcnt; if (n > OVFCAP) n = OVFCAP;
    int total = n * (F / 4);
    for (int g = blockIdx.x * 256 + threadIdx.x; g < total; g += gridDim.x * 256) {
        int k = g / (F / 4), q = g % (F / 4);
        int4 rec = ovf[k];
        float coef = __int_as_float(rec.z) * dinv[rec.x];
        float4 v = *(const float4*)&xw[(size_t)rec.x * F + q * 4];
        float* dst = &out[(size_t)rec.y * F + q * 4];
        atomicAdd(dst + 0, v.x * coef);
        atomicAdd(dst + 1, v.y * coef);
        atomicAdd(dst + 2, v.z * coef);
        atomicAdd(dst + 3, v.w * coef);
    }
}

// flag==1 only: epilogue relu(dinv*S + xw*dinv^2 + b)
template <int F>
__global__ void epi_kernel(float* __restrict__ out, const float* __restrict__ xw,
                           const float* __restrict__ dinv, const float* __restrict__ b,
                           const int* __restrict__ flag, int N) {
    if (*flag == 0) return;
    int g = blockIdx.x * 256 + threadIdx.x;
    int n = g / (F / 4), q = g % (F / 4);
    if (n >= N) return;
    float d = dinv[n], d2 = d * d;
    float4 a = ((const float4*)out)[g];
    float4 xv = ((const float4*)xw)[g];
    float4 bb = ((const float4*)b)[q];
    float4 o;
    o.x = fmaxf(a.x * d + xv.x * d2 + bb.x, 0.f);
    o.y = fmaxf(a.y * d + xv.y * d2 + bb.y, 0.f);
    o.z = fmaxf(a.z * d + xv.z * d2 + bb.z, 0.f);
    o.w = fmaxf(a.w * d + xv.w * d2 + bb.w, 0.f);
    ((float4*)out)[g] = o;
}

// sums[batch[n]] += x1[n]; cnt[batch[n]] += 1 (sorted batch, boundary atomics)
__global__ void pool_kernel(const float* __restrict__ x1, const int* __restrict__ batch,
                            float* __restrict__ sums, float* __restrict__ cnt, int N) {
    constexpr int QG = 16, S = 16, ITER = 16;
    int t = threadIdx.x;
    int q = t % QG, s = t / QG;
    int n0 = blockIdx.x * (S * ITER) + s * ITER;
    float4 acc = make_float4(0.f, 0.f, 0.f, 0.f);
    float cacc = 0.f;
    int gcur = -1;
    for (int i = 0; i < ITER; ++i) {
        int n = n0 + i;
        if (n >= N) break;
        int gid = batch[n];
        if (gid != gcur) {
            if (gcur >= 0) {
                float* dst = &sums[gcur * 64 + q * 4];
                atomicAdd(dst + 0, acc.x);
                atomicAdd(dst + 1, acc.y);
                atomicAdd(dst + 2, acc.z);
                atomicAdd(dst + 3, acc.w);
                if (q == 0) atomicAdd(&cnt[gcur], cacc);
            }
            gcur = gid;
            acc = make_float4(0.f, 0.f, 0.f, 0.f);
            cacc = 0.f;
        }
        float4 a = ((const float4*)x1)[n * QG + q];
        acc.x += a.x; acc.y += a.y; acc.z += a.z; acc.w += a.w;
        if (q == 0) cacc += 1.f;
    }
    if (gcur >= 0) {
        float* dst = &sums[gcur * 64 + q * 4];
        atomicAdd(dst + 0, acc.x);
        atomicAdd(dst + 1, acc.y);
        atomicAdd(dst + 2, acc.z);
        atomicAdd(dst + 3, acc.w);
        if (q == 0) atomicAdd(&cnt[gcur], cacc);
    }
}

// Final MLP head + log_softmax, one block. G=64 graphs.
__global__ void head_kernel(const float* __restrict__ sums, const float* __restrict__ cnt,
                            const float* __restrict__ fc1W, const float* __restrict__ fc1b,
                            const float* __restrict__ fc2W, const float* __restrict__ fc2b,
                            float* __restrict__ out) {
    __shared__ float x2[64 * 64];
    __shared__ float h[64 * 128];
    __shared__ float logits[64 * 2];
    int t = threadIdx.x;
    for (int i = t; i < 64 * 64; i += 256) {
        int g = i / 64;
        x2[i] = sums[i] / fmaxf(cnt[g], 1.f);
    }
    __syncthreads();
    for (int i = t; i < 64 * 128; i += 256) {
        int g = i / 128, k = i % 128;
        float a = fc1b[k];
        #pragma unroll 8
        for (int j = 0; j < 64; ++j) a += x2[g * 64 + j] * fc1W[j * 128 + k];
        h[i] = fmaxf(a, 0.f);
    }
    __syncthreads();
    if (t < 128) {
        int g = t / 2, m = t % 2;
        float a = fc2b[m];
        #pragma unroll 8
        for (int k = 0; k < 128; ++k) a += h[g * 128 + k] * fc2W[k * 2 + m];
        logits[t] = a;
    }
    __syncthreads();
    if (t < 128) {
        int g = t / 2, m = t % 2;
        float l0 = logits[g * 2 + 0], l1 = logits[g * 2 + 1];
        float mx = fmaxf(l0, l1);
        float lse = mx + logf(expf(l0 - mx) + expf(l1 - mx));
        out[t] = (m == 0 ? l0 : l1) - lse;
    }
}

extern "C" void kernel_launch(void* const* d_in, const int* in_sizes, int n_in,
                              void* d_out, int out_size, void* d_ws, size_t ws_size,
                              hipStream_t stream) {
    const float* x      = (const float*)d_in[0];
    const int*   eidx   = (const int*)d_in[1];
    const float* ew     = (const float*)d_in[2];
    const int*   batch  = (const int*)d_in[3];
    const float* W1     = (const float*)d_in[4];
    const float* b1     = (const float*)d_in[5];
    const float* W2     = (const float*)d_in[6];
    const float* b2     = (const float*)d_in[7];
    const float* fc1W   = (const float*)d_in[8];
    const float* fc1b   = (const float*)d_in[9];
    const float* fc2W   = (const float*)d_in[10];
    const float* fc2b   = (const float*)d_in[11];
    float* out = (float*)d_out;

    const int N = in_sizes[3];          // 50000 nodes
    const int E = in_sizes[2];          // 1600000 edges
    const int* rows = eidx;
    const int* cols = eidx + E;

    float* ws = (float*)d_ws;
    size_t off = 0;
    auto alloc = [&](size_t n) { float* p = ws + off; off += (n + 15) & ~(size_t)15; return p; };
    // --- zero-initialized region ---
    int*   cnt    = (int*)alloc(N);
    float* sums   = alloc(64 * 64);
    float* cntf   = alloc(16);
    int*   ovfcnt = (int*)alloc(16);
    int*   flag   = (int*)alloc(16);
    size_t zfloats = off;
    // --- rest ---
    float* deg    = alloc(N);
    int2*  slot   = (int2*)alloc((size_t)N * CAP * 2);
    int4*  ovf    = (int4*)alloc((size_t)OVFCAP * 4);
    float* bufA   = alloc((size_t)N * 128);   // xw1; later xw2 (lo) + x1 (hi)
    float* bufB   = alloc((size_t)N * 128);   // h
    float* xw1 = bufA;
    float* h   = bufB;
    float* xw2 = bufA;
    float* x1  = bufA + (size_t)N * 64;
    (void)ws_size;

    hipMemsetAsync(d_ws, 0, zfloats * sizeof(float), stream);

    // CSR build: bucket -> per-bucket degree -> dinv -> fold dinv[row] into coef
    place_kernel<<<(E + 255) / 256, 256, 0, stream>>>(rows, cols, ew, cnt, slot, ovf, ovfcnt, flag, E);
    degfin_kernel<<<(N + 3) / 4, 256, 0, stream>>>(slot, cnt, deg, N);
    ovfdeg_kernel<<<1, 256, 0, stream>>>(ovf, ovfcnt, deg);
    dinv_kernel<<<(N + 255) / 256, 256, 0, stream>>>(deg, N);
    rescale_kernel<<<(N * CAP + 255) / 256, 256, 0, stream>>>(slot, cnt, deg, N);

    // Layer 1
    gemm_kernel<128><<<(N + 31) / 32, 256, 0, stream>>>(x, W1, xw1, N);
    gather_kernel<128><<<(N + 3) / 4, 256, 0, stream>>>(xw1, slot, cnt, deg, b1, flag, h, N);
    ovfmsg_kernel<128><<<64, 256, 0, stream>>>(xw1, ovf, ovfcnt, deg, flag, h);
    epi_kernel<128><<<(N * 32 + 255) / 256, 256, 0, stream>>>(h, xw1, deg, b1, flag, N);

    // Layer 2
    gemm_kernel<64><<<(N + 63) / 64, 256, 0, stream>>>(h, W2, xw2, N);
    gather_kernel<64><<<(N + 3) / 4, 256, 0, stream>>>(xw2, slot, cnt, deg, b2, flag, x1, N);
    ovfmsg_kernel<64><<<64, 256, 0, stream>>>(xw2, ovf, ovfcnt, deg, flag, x1);
    epi_kernel<64><<<(N * 16 + 255) / 256, 256, 0, stream>>>(x1, xw2, deg, b2, flag, N);

    // Mean-pool + head
    pool_kernel<<<(N + 255) / 256, 256, 0, stream>>>(x1, batch, sums, cntf, N);
    head_kernel<<<1, 256, 0, stream>>>(sums, cntf, fc1W, fc1b, fc2W, fc2b, out);
}